// Round 1
// baseline (424.407 us; speedup 1.0000x reference)
//
#include <hip/hip_runtime.h>
#include <math.h>

// Workspace layout (floats):
//   gsum   [81*32]  @ 0      level-4 segment sums of z_hyp
//   gcnt   [81]     @ 2592   level-4 segment counts
//   dsum   [81*4]   @ 2673   per-s4, per-level distance sums
//   cent   [120*32] @ 2997   centroids for all 120 segments (lvl1:0-2, lvl2:3-11, lvl3:12-38, lvl4:39-119)
//   cnt_all[120]    @ 6837   counts per segment (all levels)
//   cnorm  [120]    @ 6957   ||centroid||^2 per segment
// Total 7077 floats. First 2997 are accumulators -> memset to 0 each launch.

#define MAXR 0.95f

__device__ __forceinline__ float red8(float v) {
    v += __shfl_xor(v, 1, 8);
    v += __shfl_xor(v, 2, 8);
    v += __shfl_xor(v, 4, 8);
    return v;
}

__device__ __forceinline__ float red32(float v) {
    v += __shfl_xor(v, 1, 32);
    v += __shfl_xor(v, 2, 32);
    v += __shfl_xor(v, 4, 32);
    v += __shfl_xor(v, 8, 32);
    v += __shfl_xor(v, 16, 32);
    return v;
}

// Pass 1: level-4 histogram (counts + vector sums of projected points).
// 8 lanes per point, float4 per lane (D=32).
__global__ __launch_bounds__(256) void pass1_hist(
        const float* __restrict__ z, const int* __restrict__ idx,
        float* __restrict__ gsum, float* __restrict__ gcnt, int B) {
    __shared__ float lsum[81][33];   // padded: bank = (s4 + d) % 32
    __shared__ float lcnt[81];
    const int tid = threadIdx.x;
    for (int j = tid; j < 81 * 33; j += blockDim.x) (&lsum[0][0])[j] = 0.f;
    for (int j = tid; j < 81; j += blockDim.x) lcnt[j] = 0.f;
    __syncthreads();

    const int sub = tid & 7;               // lane within point-group
    const int g0 = blockIdx.x * (blockDim.x >> 3) + (tid >> 3);
    const int gs = gridDim.x * (blockDim.x >> 3);
    for (int i = g0; i < B; i += gs) {
        float4 xv = *(const float4*)(z + (size_t)i * 32 + sub * 4);
        float nx = red8(xv.x * xv.x + xv.y * xv.y + xv.z * xv.z + xv.w * xv.w);
        float norm = sqrtf(nx);
        if (norm > MAXR) {
            float s = MAXR / (norm + 1e-12f);
            xv.x *= s; xv.y *= s; xv.z *= s; xv.w *= s;
        }
        const int s4 = idx[i] / 243;       // 3^5
        atomicAdd(&lsum[s4][sub * 4 + 0], xv.x);
        atomicAdd(&lsum[s4][sub * 4 + 1], xv.y);
        atomicAdd(&lsum[s4][sub * 4 + 2], xv.z);
        atomicAdd(&lsum[s4][sub * 4 + 3], xv.w);
        if (sub == 0) atomicAdd(&lcnt[s4], 1.0f);
    }
    __syncthreads();
    for (int j = tid; j < 81 * 32; j += blockDim.x)
        atomicAdd(&gsum[j], lsum[j >> 5][j & 31]);
    for (int j = tid; j < 81; j += blockDim.x)
        atomicAdd(&gcnt[j], lcnt[j]);
}

// Pass 2: aggregate hierarchy + Frechet-mean iteration for all 120 segments.
// One 32-lane group per segment (lane = dim).
__global__ __launch_bounds__(256) void pass2_centroids(
        const float* __restrict__ gsum, const float* __restrict__ gcnt,
        float* __restrict__ cent, float* __restrict__ cnt_all,
        float* __restrict__ cnorm) {
    const int tid = threadIdx.x;
    const int lane = tid & 31;
    const int grp = tid >> 5;
    for (int t = grp; t < 120; t += (blockDim.x >> 5)) {
        int c0, n;
        if (t < 3)       { c0 = t * 27;        n = 27; }
        else if (t < 12) { c0 = (t - 3) * 9;   n = 9;  }
        else if (t < 39) { c0 = (t - 12) * 3;  n = 3;  }
        else             { c0 = (t - 39);      n = 1;  }
        float sum = 0.f, cnt = 0.f;
        for (int k = 0; k < n; ++k) {
            sum += gsum[(c0 + k) * 32 + lane];
            cnt += gcnt[c0 + k];
        }
        const float em = sum / fmaxf(cnt, 1.0f);
        // mean = project(euc_mean)
        float m = em;
        {
            float norm = sqrtf(red32(m * m));
            if (norm > MAXR) m *= MAXR / (norm + 1e-12f);
        }
        // 10 Frechet iterations
        for (int it = 0; it < 10; ++it) {
            float v = m + 0.1f * (em - m);
            float norm = sqrtf(red32(v * v));
            if (norm > MAXR) v *= MAXR / (norm + 1e-12f);
            m = v;
        }
        cent[t * 32 + lane] = m;
        float ny = red32(m * m);
        if (lane == 0) { cnt_all[t] = cnt; cnorm[t] = ny; }
    }
}

// Pass 3: per-point distances to the 4 ancestor centroids, accumulated
// per-(s4, level). Centroids staged in LDS.
__global__ __launch_bounds__(256) void pass3_dist(
        const float* __restrict__ z, const int* __restrict__ idx,
        const float* __restrict__ cent, const float* __restrict__ cnorm,
        float* __restrict__ dsum, int B) {
    __shared__ float lcent[120 * 32];
    __shared__ float lcn[120];
    __shared__ float ld[81][4];
    const int tid = threadIdx.x;
    for (int j = tid; j < 120 * 32; j += blockDim.x) lcent[j] = cent[j];
    for (int j = tid; j < 120; j += blockDim.x) lcn[j] = cnorm[j];
    for (int j = tid; j < 81 * 4; j += blockDim.x) (&ld[0][0])[j] = 0.f;
    __syncthreads();

    const int sub = tid & 7;
    const int g0 = blockIdx.x * (blockDim.x >> 3) + (tid >> 3);
    const int gs = gridDim.x * (blockDim.x >> 3);
    for (int i = g0; i < B; i += gs) {
        float4 xv = *(const float4*)(z + (size_t)i * 32 + sub * 4);
        float nx = red8(xv.x * xv.x + xv.y * xv.y + xv.z * xv.z + xv.w * xv.w);
        float norm = sqrtf(nx);
        if (norm > MAXR) {
            float s = MAXR / (norm + 1e-12f);
            xv.x *= s; xv.y *= s; xv.z *= s; xv.w *= s;
            nx = nx * s * s;
        }
        const int s4 = idx[i] / 243;
        const float omx = 1.0f - nx;
        // level l (1..4): ancestor segment = s4 / 3^(4-l), offset into cent table
        const int toff[4] = {0, 3, 12, 39};
        const int tdiv[4] = {27, 9, 3, 1};
#pragma unroll
        for (int l = 0; l < 4; ++l) {
            const int t = toff[l] + s4 / tdiv[l];
            const float4 c = *(const float4*)(lcent + t * 32 + sub * 4);
            float dx = xv.x - c.x, dy = xv.y - c.y, dz = xv.z - c.z, dw = xv.w - c.w;
            float sq = red8(dx * dx + dy * dy + dz * dz + dw * dw);
            float ny = lcn[t];
            float denom = fmaxf(omx * (1.0f - ny), 1e-12f);
            float arg = 1.0f + 2.0f * sq / denom;
            arg = fmaxf(arg, 1.0f + 1e-7f);
            float dist = acoshf(arg);
            if (sub == 0) atomicAdd(&ld[s4][l], dist);
        }
    }
    __syncthreads();
    for (int j = tid; j < 81 * 4; j += blockDim.x)
        atomicAdd(&dsum[j], (&ld[0][0])[j]);
}

// Pass 4: finalize — aggregate per-level, apply valid/count logic, weighted sum.
__global__ __launch_bounds__(128) void pass4_final(
        const float* __restrict__ dsum, const float* __restrict__ cnt_all,
        const float* __restrict__ w, float* __restrict__ out) {
    __shared__ float sl[81];
    __shared__ float su[81];
    const int tid = threadIdx.x;
    const int toff[4] = {0, 3, 12, 39};
    const int nsegs[4] = {3, 9, 27, 81};
    float total = 0.f;
    for (int l = 0; l < 4; ++l) {
        const int n_seg = nsegs[l];
        const int ch = 81 / n_seg;
        __syncthreads();
        if (tid < n_seg) {
            float cnt = cnt_all[toff[l] + tid];
            float ds = 0.f;
            for (int k = 0; k < ch; ++k) ds += dsum[(tid * ch + k) * 4 + l];
            sl[tid] = (cnt >= 2.0f) ? ds / fmaxf(cnt, 1.0f) : 0.f;
            su[tid] = (cnt > 0.0f) ? 1.f : 0.f;
        }
        __syncthreads();
        if (tid == 0) {
            float ll = 0.f, nu = 0.f;
            for (int s = 0; s < n_seg; ++s) { ll += sl[s]; nu += su[s]; }
            total += w[l] * ll / fmaxf(nu, 1.0f);
        }
    }
    if (tid == 0) out[0] = total;
}

extern "C" void kernel_launch(void* const* d_in, const int* in_sizes, int n_in,
                              void* d_out, int out_size, void* d_ws, size_t ws_size,
                              hipStream_t stream) {
    const float* z   = (const float*)d_in[0];
    const int*   idx = (const int*)d_in[1];
    const float* w   = (const float*)d_in[2];
    float* out = (float*)d_out;
    float* ws  = (float*)d_ws;
    const int B = in_sizes[1];

    float* gsum    = ws;          // 2592
    float* gcnt    = ws + 2592;   // 81
    float* dsum    = ws + 2673;   // 324
    float* cent    = ws + 2997;   // 3840
    float* cnt_all = ws + 6837;   // 120
    float* cnorm   = ws + 6957;   // 120

    hipMemsetAsync(ws, 0, 2997 * sizeof(float), stream);
    pass1_hist<<<1024, 256, 0, stream>>>(z, idx, gsum, gcnt, B);
    pass2_centroids<<<1, 256, 0, stream>>>(gsum, gcnt, cent, cnt_all, cnorm);
    pass3_dist<<<1024, 256, 0, stream>>>(z, idx, cent, cnorm, dsum, B);
    pass4_final<<<1, 128, 0, stream>>>(dsum, cnt_all, w, out);
}

// Round 2
// 400.592 us; speedup vs baseline: 1.0595x; 1.0595x over previous
//
#include <hip/hip_runtime.h>
#include <math.h>

// Workspace layout (floats):
//   gsum   [81*32]  @ 0      level-4 segment sums of z_hyp
//   gcnt   [81]     @ 2592   level-4 segment counts
//   dsum   [81*4]   @ 2673   per-s4, per-level distance sums
//   cent   [120*32] @ 2997   centroids for all 120 segments (lvl1:0-2, lvl2:3-11, lvl3:12-38, lvl4:39-119)
//   cnt_all[120]    @ 6837   counts per segment (all levels)
//   cnorm  [120]    @ 6957   ||centroid||^2 per segment
// Total 7077 floats. First 2997 are accumulators -> memset to 0 each launch.

#define MAXR 0.95f

// Native no-return f32 atomic (ds_add_f32 / global_atomic_add_f32).
// Plain atomicAdd(float*) may lower to a CAS retry loop; unsafeAtomicAdd
// forces the fire-and-forget HW atomic on gfx950.
__device__ __forceinline__ void atomAddF(float* p, float v) {
    unsafeAtomicAdd(p, v);
}

__device__ __forceinline__ float red8(float v) {
    v += __shfl_xor(v, 1, 8);
    v += __shfl_xor(v, 2, 8);
    v += __shfl_xor(v, 4, 8);
    return v;
}

__device__ __forceinline__ float red32(float v) {
    v += __shfl_xor(v, 1, 32);
    v += __shfl_xor(v, 2, 32);
    v += __shfl_xor(v, 4, 32);
    v += __shfl_xor(v, 8, 32);
    v += __shfl_xor(v, 16, 32);
    return v;
}

// Pass 1: level-4 histogram (counts + vector sums of projected points).
// 8 lanes per point, float4 per lane (D=32). Two privatized LDS copies
// (waves split on tid bit 7) to halve atomic contention.
__global__ __launch_bounds__(256) void pass1_hist(
        const float* __restrict__ z, const int* __restrict__ idx,
        float* __restrict__ gsum, float* __restrict__ gcnt, int B) {
    __shared__ float lsum[2][81][33];   // padded: bank = (s4 + d) % 32
    __shared__ float lcnt[2][81];
    const int tid = threadIdx.x;
    for (int j = tid; j < 2 * 81 * 33; j += blockDim.x) (&lsum[0][0][0])[j] = 0.f;
    for (int j = tid; j < 2 * 81; j += blockDim.x) (&lcnt[0][0])[j] = 0.f;
    __syncthreads();

    const int cp = (tid >> 7) & 1;         // LDS copy selector
    const int sub = tid & 7;               // lane within point-group
    const int g0 = blockIdx.x * (blockDim.x >> 3) + (tid >> 3);
    const int gs = gridDim.x * (blockDim.x >> 3);
    for (int i = g0; i < B; i += gs) {
        float4 xv = *(const float4*)(z + (size_t)i * 32 + sub * 4);
        const int s4 = idx[i] / 243;       // 3^5
        float nx = red8(xv.x * xv.x + xv.y * xv.y + xv.z * xv.z + xv.w * xv.w);
        float norm = sqrtf(nx);
        if (norm > MAXR) {
            float s = MAXR / (norm + 1e-12f);
            xv.x *= s; xv.y *= s; xv.z *= s; xv.w *= s;
        }
        atomAddF(&lsum[cp][s4][sub * 4 + 0], xv.x);
        atomAddF(&lsum[cp][s4][sub * 4 + 1], xv.y);
        atomAddF(&lsum[cp][s4][sub * 4 + 2], xv.z);
        atomAddF(&lsum[cp][s4][sub * 4 + 3], xv.w);
        if (sub == 0) atomAddF(&lcnt[cp][s4], 1.0f);
    }
    __syncthreads();
    for (int j = tid; j < 81 * 32; j += blockDim.x)
        atomAddF(&gsum[j], lsum[0][j >> 5][j & 31] + lsum[1][j >> 5][j & 31]);
    for (int j = tid; j < 81; j += blockDim.x)
        atomAddF(&gcnt[j], lcnt[0][j] + lcnt[1][j]);
}

// Pass 2: aggregate hierarchy + Frechet-mean iteration for all 120 segments.
// One 32-lane group per segment (lane = dim).
__global__ __launch_bounds__(256) void pass2_centroids(
        const float* __restrict__ gsum, const float* __restrict__ gcnt,
        float* __restrict__ cent, float* __restrict__ cnt_all,
        float* __restrict__ cnorm) {
    const int tid = threadIdx.x;
    const int lane = tid & 31;
    const int grp = tid >> 5;
    for (int t = grp; t < 120; t += (blockDim.x >> 5)) {
        int c0, n;
        if (t < 3)       { c0 = t * 27;        n = 27; }
        else if (t < 12) { c0 = (t - 3) * 9;   n = 9;  }
        else if (t < 39) { c0 = (t - 12) * 3;  n = 3;  }
        else             { c0 = (t - 39);      n = 1;  }
        float sum = 0.f, cnt = 0.f;
        for (int k = 0; k < n; ++k) {
            sum += gsum[(c0 + k) * 32 + lane];
            cnt += gcnt[c0 + k];
        }
        const float em = sum / fmaxf(cnt, 1.0f);
        // mean = project(euc_mean)
        float m = em;
        {
            float norm = sqrtf(red32(m * m));
            if (norm > MAXR) m *= MAXR / (norm + 1e-12f);
        }
        // 10 Frechet iterations
        for (int it = 0; it < 10; ++it) {
            float v = m + 0.1f * (em - m);
            float norm = sqrtf(red32(v * v));
            if (norm > MAXR) v *= MAXR / (norm + 1e-12f);
            m = v;
        }
        cent[t * 32 + lane] = m;
        float ny = red32(m * m);
        if (lane == 0) { cnt_all[t] = cnt; cnorm[t] = ny; }
    }
}

// Pass 3: per-point distances to the 4 ancestor centroids, accumulated
// per-(s4, level). Centroids staged in LDS.
__global__ __launch_bounds__(256) void pass3_dist(
        const float* __restrict__ z, const int* __restrict__ idx,
        const float* __restrict__ cent, const float* __restrict__ cnorm,
        float* __restrict__ dsum, int B) {
    __shared__ float lcent[120 * 32];
    __shared__ float lcn[120];
    __shared__ float ld[81][4];
    const int tid = threadIdx.x;
    for (int j = tid; j < 120 * 32; j += blockDim.x) lcent[j] = cent[j];
    for (int j = tid; j < 120; j += blockDim.x) lcn[j] = cnorm[j];
    for (int j = tid; j < 81 * 4; j += blockDim.x) (&ld[0][0])[j] = 0.f;
    __syncthreads();

    const int sub = tid & 7;
    const int g0 = blockIdx.x * (blockDim.x >> 3) + (tid >> 3);
    const int gs = gridDim.x * (blockDim.x >> 3);
    for (int i = g0; i < B; i += gs) {
        float4 xv = *(const float4*)(z + (size_t)i * 32 + sub * 4);
        const int s4 = idx[i] / 243;
        float nx = red8(xv.x * xv.x + xv.y * xv.y + xv.z * xv.z + xv.w * xv.w);
        float norm = sqrtf(nx);
        if (norm > MAXR) {
            float s = MAXR / (norm + 1e-12f);
            xv.x *= s; xv.y *= s; xv.z *= s; xv.w *= s;
            nx = nx * s * s;
        }
        const float omx = 1.0f - nx;
        // level l (1..4): ancestor segment = s4 / 3^(4-l), offset into cent table
        const int toff[4] = {0, 3, 12, 39};
        const int tdiv[4] = {27, 9, 3, 1};
#pragma unroll
        for (int l = 0; l < 4; ++l) {
            const int t = toff[l] + s4 / tdiv[l];
            const float4 c = *(const float4*)(lcent + t * 32 + sub * 4);
            float dx = xv.x - c.x, dy = xv.y - c.y, dz = xv.z - c.z, dw = xv.w - c.w;
            float sq = red8(dx * dx + dy * dy + dz * dz + dw * dw);
            float ny = lcn[t];
            float denom = fmaxf(omx * (1.0f - ny), 1e-12f);
            float arg = 1.0f + 2.0f * sq / denom;
            arg = fmaxf(arg, 1.0f + 1e-7f);
            float dist = acoshf(arg);
            if (sub == 0) atomAddF(&ld[s4][l], dist);
        }
    }
    __syncthreads();
    for (int j = tid; j < 81 * 4; j += blockDim.x)
        atomAddF(&dsum[j], (&ld[0][0])[j]);
}

// Pass 4: finalize — aggregate per-level, apply valid/count logic, weighted sum.
__global__ __launch_bounds__(128) void pass4_final(
        const float* __restrict__ dsum, const float* __restrict__ cnt_all,
        const float* __restrict__ w, float* __restrict__ out) {
    __shared__ float sl[81];
    __shared__ float su[81];
    const int tid = threadIdx.x;
    const int toff[4] = {0, 3, 12, 39};
    const int nsegs[4] = {3, 9, 27, 81};
    float total = 0.f;
    for (int l = 0; l < 4; ++l) {
        const int n_seg = nsegs[l];
        const int ch = 81 / n_seg;
        __syncthreads();
        if (tid < n_seg) {
            float cnt = cnt_all[toff[l] + tid];
            float ds = 0.f;
            for (int k = 0; k < ch; ++k) ds += dsum[(tid * ch + k) * 4 + l];
            sl[tid] = (cnt >= 2.0f) ? ds / fmaxf(cnt, 1.0f) : 0.f;
            su[tid] = (cnt > 0.0f) ? 1.f : 0.f;
        }
        __syncthreads();
        if (tid == 0) {
            float ll = 0.f, nu = 0.f;
            for (int s = 0; s < n_seg; ++s) { ll += sl[s]; nu += su[s]; }
            total += w[l] * ll / fmaxf(nu, 1.0f);
        }
    }
    if (tid == 0) out[0] = total;
}

extern "C" void kernel_launch(void* const* d_in, const int* in_sizes, int n_in,
                              void* d_out, int out_size, void* d_ws, size_t ws_size,
                              hipStream_t stream) {
    const float* z   = (const float*)d_in[0];
    const int*   idx = (const int*)d_in[1];
    const float* w   = (const float*)d_in[2];
    float* out = (float*)d_out;
    float* ws  = (float*)d_ws;
    const int B = in_sizes[1];

    float* gsum    = ws;          // 2592
    float* gcnt    = ws + 2592;   // 81
    float* dsum    = ws + 2673;   // 324
    float* cent    = ws + 2997;   // 3840
    float* cnt_all = ws + 6837;   // 120
    float* cnorm   = ws + 6957;   // 120

    hipMemsetAsync(ws, 0, 2997 * sizeof(float), stream);
    pass1_hist<<<2048, 256, 0, stream>>>(z, idx, gsum, gcnt, B);
    pass2_centroids<<<1, 256, 0, stream>>>(gsum, gcnt, cent, cnt_all, cnorm);
    pass3_dist<<<2048, 256, 0, stream>>>(z, idx, cent, cnorm, dsum, B);
    pass4_final<<<1, 128, 0, stream>>>(dsum, cnt_all, w, out);
}

// Round 3
// 310.825 us; speedup vs baseline: 1.3654x; 1.2888x over previous
//
#include <hip/hip_runtime.h>
#include <math.h>

// Workspace layout (floats):
//   gsum   [81*32]  @ 0      level-4 segment sums of z_hyp
//   gcnt   [81]     @ 2592   level-4 segment counts
//   dsum   [81*4]   @ 2673   per-s4, per-level distance sums
//   cent   [120*32] @ 2997   centroids (lvl1:0-2, lvl2:3-11, lvl3:12-38, lvl4:39-119)
//   cnt_all[120]    @ 6837
//   cnorm  [120]    @ 6957
// First 2997 floats are accumulators -> memset to 0 each launch.

#define MAXR 0.95f

__device__ __forceinline__ float red8(float v) {
    v += __shfl_xor(v, 1, 8);
    v += __shfl_xor(v, 2, 8);
    v += __shfl_xor(v, 4, 8);
    return v;
}

__device__ __forceinline__ float red32(float v) {
    v += __shfl_xor(v, 1, 32);
    v += __shfl_xor(v, 2, 32);
    v += __shfl_xor(v, 4, 32);
    v += __shfl_xor(v, 8, 32);
    v += __shfl_xor(v, 16, 32);
    return v;
}

// rank of this 8-lane group among same-s4 groups in the wave (for RMW rounds).
// Lane (g,sub) reads group sub's s4 via bpermute; ballot bit (g*8+sub) says
// "group sub's s4 == group g's s4"; rank_g = popc of bits for groups < g.
__device__ __forceinline__ int dup_rank(int s4, int g, int sub) {
    int sj = __shfl(s4, sub * 8, 64);
    unsigned long long eq = __ballot(sj == s4);
    unsigned int row = (unsigned int)(eq >> (g * 8));
    return __popc(row & ((1u << g) - 1u));
}

// Pass 1: level-4 histogram (counts + vector sums of projected points).
// 8 lanes per point, float4 per lane. Per-WAVE private LDS copy, non-atomic
// RMW with rank-round duplicate serialization. Row stride 36 (b128-aligned;
// col 32 = count).
__global__ __launch_bounds__(256) void pass1_hist(
        const float* __restrict__ z, const int* __restrict__ idx,
        float* __restrict__ gsum, float* __restrict__ gcnt, int B) {
    __shared__ float lsum[4][81][36];
    const int tid = threadIdx.x;
    for (int j = tid; j < 4 * 81 * 36; j += 256) (&lsum[0][0][0])[j] = 0.f;
    __syncthreads();

    const int w = tid >> 6;
    const int g = (tid & 63) >> 3;
    const int sub = tid & 7;
    const int g0 = blockIdx.x * 32 + (tid >> 3);
    const int gs = gridDim.x * 32;

    int i = g0;
    float4 xv = {0, 0, 0, 0};
    int s4 = 0;
    if (i < B) {
        xv = *(const float4*)(z + (size_t)i * 32 + sub * 4);
        s4 = idx[i] / 243;
    }
    while (i < B) {
        const int inext = i + gs;
        float4 xn = {0, 0, 0, 0};
        int sn = 0;
        if (inext < B) {                       // prefetch next point
            xn = *(const float4*)(z + (size_t)inext * 32 + sub * 4);
            sn = idx[inext] / 243;
        }
        // project to Poincare ball
        float nx = red8(xv.x * xv.x + xv.y * xv.y + xv.z * xv.z + xv.w * xv.w);
        float norm = sqrtf(nx);
        if (norm > MAXR) {
            float s = MAXR / (norm + 1e-12f);
            xv.x *= s; xv.y *= s; xv.z *= s; xv.w *= s;
        }
        const int rank = dup_rank(s4, g, sub);
        float* row = &lsum[w][s4][0];
        for (int r = 0; ; ++r) {
            if (!__any(rank == r)) break;
            if (rank == r) {
                float4 cur = *(float4*)(row + sub * 4);
                cur.x += xv.x; cur.y += xv.y; cur.z += xv.z; cur.w += xv.w;
                *(float4*)(row + sub * 4) = cur;
                if (sub == 0) row[32] += 1.0f;
            }
        }
        i = inext; xv = xn; s4 = sn;
    }
    __syncthreads();
    for (int j = tid; j < 81 * 33; j += 256) {
        const int r = j / 33, c = j % 33;
        const float v = lsum[0][r][c] + lsum[1][r][c] + lsum[2][r][c] + lsum[3][r][c];
        if (c < 32) unsafeAtomicAdd(&gsum[r * 32 + c], v);
        else        unsafeAtomicAdd(&gcnt[r], v);
    }
}

// Pass 2: aggregate hierarchy + Frechet-mean iteration for all 120 segments.
__global__ __launch_bounds__(256) void pass2_centroids(
        const float* __restrict__ gsum, const float* __restrict__ gcnt,
        float* __restrict__ cent, float* __restrict__ cnt_all,
        float* __restrict__ cnorm) {
    const int tid = threadIdx.x;
    const int lane = tid & 31;
    const int grp = tid >> 5;
    for (int t = grp; t < 120; t += (blockDim.x >> 5)) {
        int c0, n;
        if (t < 3)       { c0 = t * 27;        n = 27; }
        else if (t < 12) { c0 = (t - 3) * 9;   n = 9;  }
        else if (t < 39) { c0 = (t - 12) * 3;  n = 3;  }
        else             { c0 = (t - 39);      n = 1;  }
        float sum = 0.f, cnt = 0.f;
        for (int k = 0; k < n; ++k) {
            sum += gsum[(c0 + k) * 32 + lane];
            cnt += gcnt[c0 + k];
        }
        const float em = sum / fmaxf(cnt, 1.0f);
        float m = em;
        {
            float norm = sqrtf(red32(m * m));
            if (norm > MAXR) m *= MAXR / (norm + 1e-12f);
        }
        for (int it = 0; it < 10; ++it) {
            float v = m + 0.1f * (em - m);
            float norm = sqrtf(red32(v * v));
            if (norm > MAXR) v *= MAXR / (norm + 1e-12f);
            m = v;
        }
        cent[t * 32 + lane] = m;
        float ny = red32(m * m);
        if (lane == 0) { cnt_all[t] = cnt; cnorm[t] = ny; }
    }
}

// Pass 3: per-point distances to the 4 ancestor centroids. Per-wave private
// [81][4] LDS accumulator, rank-round RMW (sub==0 lanes), fast acosh.
__global__ __launch_bounds__(256) void pass3_dist(
        const float* __restrict__ z, const int* __restrict__ idx,
        const float* __restrict__ cent, const float* __restrict__ cnorm,
        float* __restrict__ dsum, int B) {
    __shared__ float lcent[120 * 32];
    __shared__ float lcn[120];
    __shared__ float ld[4][81][4];
    const int tid = threadIdx.x;
    for (int j = tid; j < 120 * 32; j += 256) lcent[j] = cent[j];
    for (int j = tid; j < 120; j += 256) lcn[j] = cnorm[j];
    for (int j = tid; j < 4 * 81 * 4; j += 256) (&ld[0][0][0])[j] = 0.f;
    __syncthreads();

    const int w = tid >> 6;
    const int g = (tid & 63) >> 3;
    const int sub = tid & 7;
    const int g0 = blockIdx.x * 32 + (tid >> 3);
    const int gs = gridDim.x * 32;

    int i = g0;
    float4 xv = {0, 0, 0, 0};
    int s4 = 0;
    if (i < B) {
        xv = *(const float4*)(z + (size_t)i * 32 + sub * 4);
        s4 = idx[i] / 243;
    }
    while (i < B) {
        const int inext = i + gs;
        float4 xn = {0, 0, 0, 0};
        int sn = 0;
        if (inext < B) {
            xn = *(const float4*)(z + (size_t)inext * 32 + sub * 4);
            sn = idx[inext] / 243;
        }
        float nx = red8(xv.x * xv.x + xv.y * xv.y + xv.z * xv.z + xv.w * xv.w);
        float norm = sqrtf(nx);
        if (norm > MAXR) {
            float s = MAXR / (norm + 1e-12f);
            xv.x *= s; xv.y *= s; xv.z *= s; xv.w *= s;
            nx = nx * s * s;
        }
        const float omx = 1.0f - nx;
        const int toff[4] = {0, 3, 12, 39};
        const int tdiv[4] = {27, 9, 3, 1};
        float dl[4];
#pragma unroll
        for (int l = 0; l < 4; ++l) {
            const int t = toff[l] + s4 / tdiv[l];
            const float4 c = *(const float4*)(lcent + t * 32 + sub * 4);
            const float dx = xv.x - c.x, dy = xv.y - c.y,
                        dz = xv.z - c.z, dw = xv.w - c.w;
            const float sq = red8(dx * dx + dy * dy + dz * dz + dw * dw);
            const float ny = lcn[t];
            const float denom = fmaxf(omx * (1.0f - ny), 1e-12f);
            float tt = 2.0f * sq * __builtin_amdgcn_rcpf(denom);
            tt = fmaxf(tt, 1e-7f);
            // arccosh(1+t) = ln(1 + t + sqrt(t*(t+2)))
            dl[l] = __log2f(1.0f + tt + sqrtf(tt * (tt + 2.0f))) * 0.69314718056f;
        }
        const int rank = dup_rank(s4, g, sub);
        float* row = &ld[w][s4][0];
        for (int r = 0; ; ++r) {
            if (!__any(rank == r)) break;
            if (rank == r && sub == 0) {
                float4 cur = *(float4*)row;
                cur.x += dl[0]; cur.y += dl[1]; cur.z += dl[2]; cur.w += dl[3];
                *(float4*)row = cur;
            }
        }
        i = inext; xv = xn; s4 = sn;
    }
    __syncthreads();
    for (int j = tid; j < 81 * 4; j += 256) {
        const float v = (&ld[0][0][0])[j] + (&ld[1][0][0])[j] +
                        (&ld[2][0][0])[j] + (&ld[3][0][0])[j];
        unsafeAtomicAdd(&dsum[j], v);
    }
}

// Pass 4: finalize.
__global__ __launch_bounds__(128) void pass4_final(
        const float* __restrict__ dsum, const float* __restrict__ cnt_all,
        const float* __restrict__ w, float* __restrict__ out) {
    __shared__ float sl[81];
    __shared__ float su[81];
    const int tid = threadIdx.x;
    const int toff[4] = {0, 3, 12, 39};
    const int nsegs[4] = {3, 9, 27, 81};
    float total = 0.f;
    for (int l = 0; l < 4; ++l) {
        const int n_seg = nsegs[l];
        const int ch = 81 / n_seg;
        __syncthreads();
        if (tid < n_seg) {
            float cnt = cnt_all[toff[l] + tid];
            float ds = 0.f;
            for (int k = 0; k < ch; ++k) ds += dsum[(tid * ch + k) * 4 + l];
            sl[tid] = (cnt >= 2.0f) ? ds / fmaxf(cnt, 1.0f) : 0.f;
            su[tid] = (cnt > 0.0f) ? 1.f : 0.f;
        }
        __syncthreads();
        if (tid == 0) {
            float ll = 0.f, nu = 0.f;
            for (int s = 0; s < n_seg; ++s) { ll += sl[s]; nu += su[s]; }
            total += w[l] * ll / fmaxf(nu, 1.0f);
        }
    }
    if (tid == 0) out[0] = total;
}

extern "C" void kernel_launch(void* const* d_in, const int* in_sizes, int n_in,
                              void* d_out, int out_size, void* d_ws, size_t ws_size,
                              hipStream_t stream) {
    const float* z   = (const float*)d_in[0];
    const int*   idx = (const int*)d_in[1];
    const float* w   = (const float*)d_in[2];
    float* out = (float*)d_out;
    float* ws  = (float*)d_ws;
    const int B = in_sizes[1];

    float* gsum    = ws;          // 2592
    float* gcnt    = ws + 2592;   // 81
    float* dsum    = ws + 2673;   // 324
    float* cent    = ws + 2997;   // 3840
    float* cnt_all = ws + 6837;   // 120
    float* cnorm   = ws + 6957;   // 120

    hipMemsetAsync(ws, 0, 2997 * sizeof(float), stream);
    pass1_hist<<<768, 256, 0, stream>>>(z, idx, gsum, gcnt, B);
    pass2_centroids<<<1, 256, 0, stream>>>(gsum, gcnt, cent, cnt_all, cnorm);
    pass3_dist<<<1024, 256, 0, stream>>>(z, idx, cent, cnorm, dsum, B);
    pass4_final<<<1, 128, 0, stream>>>(dsum, cnt_all, w, out);
}

// Round 4
// 194.216 us; speedup vs baseline: 2.1852x; 1.6004x over previous
//
#include <hip/hip_runtime.h>
#include <math.h>

// Workspace layout (floats):
//   gsum   [81*32]  @ 0      level-4 segment sums of z_hyp
//   dsum   [81*4]   @ 2592   per-s4, per-level distance sums
//   gcnt_i [81]     @ 2916   (int) level-4 segment counts
//   cent   [120*32] @ 2997   centroids (lvl1:0-2, lvl2:3-11, lvl3:12-38, lvl4:39-119)
//   cnt_all[120]    @ 6837
//   cnorm  [120]    @ 6957
// First 2997 floats are accumulators -> memset to 0 each launch.

#define MAXR 0.95f

// 8-lane sum reduction entirely in the VALU pipe via DPP (no LDS/DS ops):
// xor1 = quad_perm{1,0,3,2}=0xB1, xor2 = quad_perm{2,3,0,1}=0x4E,
// cross-quad within 8 = row_half_mirror = 0x141.
__device__ __forceinline__ float red8_dpp(float v) {
    v += __int_as_float(__builtin_amdgcn_update_dpp(0, __float_as_int(v), 0xB1, 0xF, 0xF, 1));
    v += __int_as_float(__builtin_amdgcn_update_dpp(0, __float_as_int(v), 0x4E, 0xF, 0xF, 1));
    v += __int_as_float(__builtin_amdgcn_update_dpp(0, __float_as_int(v), 0x141, 0xF, 0xF, 1));
    return v;
}

__device__ __forceinline__ float red32(float v) {
    v += __shfl_xor(v, 1, 32);
    v += __shfl_xor(v, 2, 32);
    v += __shfl_xor(v, 4, 32);
    v += __shfl_xor(v, 8, 32);
    v += __shfl_xor(v, 16, 32);
    return v;
}

// rank of this 8-lane group among same-s4 groups in the wave (RMW rounds).
__device__ __forceinline__ int dup_rank(int s4, int g, int sub) {
    int sj = __shfl(s4, sub * 8, 64);
    unsigned long long eq = __ballot(sj == s4);
    unsigned int row = (unsigned int)(eq >> (g * 8));
    return __popc(row & ((1u << g) - 1u));
}

// Pass 0: counts per level-4 segment. Native int LDS atomics.
__global__ __launch_bounds__(256) void pass0_count(
        const int* __restrict__ idx, int* __restrict__ gcnt_i, int B) {
    __shared__ int h[81];
    const int tid = threadIdx.x;
    for (int j = tid; j < 81; j += 256) h[j] = 0;
    __syncthreads();
    const int n4 = B >> 2;
    const int gstride = gridDim.x * 256;
    for (int i = blockIdx.x * 256 + tid; i < n4; i += gstride) {
        int4 v = ((const int4*)idx)[i];
        atomicAdd(&h[v.x / 243], 1);
        atomicAdd(&h[v.y / 243], 1);
        atomicAdd(&h[v.z / 243], 1);
        atomicAdd(&h[v.w / 243], 1);
    }
    for (int i = (n4 << 2) + blockIdx.x * 256 + tid; i < B; i += gstride)
        atomicAdd(&h[idx[i] / 243], 1);
    __syncthreads();
    for (int j = tid; j < 81; j += 256) if (h[j]) atomicAdd(&gcnt_i[j], h[j]);
}

// Pass 1: level-4 vector-sum histogram. 8 lanes/point, 4 points per wave-iter
// batched for ILP/MLP; DPP reductions; per-wave private LDS copy, non-atomic
// RMW with rank-round duplicate serialization. Row stride 36 (b128-aligned).
__global__ __launch_bounds__(256) void pass1_hist(
        const float* __restrict__ z, const int* __restrict__ idx,
        float* __restrict__ gsum, int B) {
    __shared__ float lsum[4][81][36];
    const int tid = threadIdx.x;
    for (int j = tid; j < 4 * 81 * 36; j += 256) (&lsum[0][0][0])[j] = 0.f;
    __syncthreads();

    const int w = tid >> 6;
    const int g = (tid & 63) >> 3;
    const int sub = tid & 7;
    const int STRIDE = gridDim.x * 128;          // points per grid-iteration
    const int base0 = blockIdx.x * 128 + w * 32 + g;
    const int nfull = B / STRIDE;
    float* const lw = &lsum[w][0][0];

    for (int it = 0; it < nfull; ++it) {
        const int ib = it * STRIDE + base0;
        float4 xv[4];
        int s4v[4], rank[4];
#pragma unroll
        for (int b = 0; b < 4; ++b)
            xv[b] = *(const float4*)(z + (size_t)(ib + b * 8) * 32 + sub * 4);
#pragma unroll
        for (int b = 0; b < 4; ++b)
            s4v[b] = idx[ib + b * 8] / 243;
#pragma unroll
        for (int b = 0; b < 4; ++b) {
            float nx = red8_dpp(xv[b].x * xv[b].x + xv[b].y * xv[b].y +
                                xv[b].z * xv[b].z + xv[b].w * xv[b].w);
            float norm = sqrtf(nx);
            if (norm > MAXR) {
                float s = MAXR / (norm + 1e-12f);
                xv[b].x *= s; xv[b].y *= s; xv[b].z *= s; xv[b].w *= s;
            }
        }
#pragma unroll
        for (int b = 0; b < 4; ++b)
            rank[b] = dup_rank(s4v[b], g, sub);
#pragma unroll
        for (int b = 0; b < 4; ++b) {
            float* row = lw + s4v[b] * 36;
            for (int r = 0;; ++r) {
                if (!__any(rank[b] == r)) break;
                if (rank[b] == r) {
                    float4 cur = *(float4*)(row + sub * 4);
                    cur.x += xv[b].x; cur.y += xv[b].y;
                    cur.z += xv[b].z; cur.w += xv[b].w;
                    *(float4*)(row + sub * 4) = cur;
                }
            }
        }
    }
    // generic tail (not executed for B = 1M with grid 512)
    if (B % STRIDE) {
        const int ib = nfull * STRIDE + base0;
        for (int b = 0; b < 4; ++b) {
            const int i = ib + b * 8;
            const bool act = i < B;
            float4 xv = act ? *(const float4*)(z + (size_t)i * 32 + sub * 4)
                            : make_float4(0.f, 0.f, 0.f, 0.f);
            int s4 = act ? idx[i] / 243 : 81 + g;
            float nx = red8_dpp(xv.x * xv.x + xv.y * xv.y + xv.z * xv.z + xv.w * xv.w);
            float norm = sqrtf(nx);
            if (norm > MAXR) {
                float s = MAXR / (norm + 1e-12f);
                xv.x *= s; xv.y *= s; xv.z *= s; xv.w *= s;
            }
            int rank = dup_rank(s4, g, sub);
            for (int r = 0;; ++r) {
                if (!__any(rank == r)) break;
                if (act && rank == r) {
                    float* row = lw + s4 * 36;
                    float4 cur = *(float4*)(row + sub * 4);
                    cur.x += xv.x; cur.y += xv.y; cur.z += xv.z; cur.w += xv.w;
                    *(float4*)(row + sub * 4) = cur;
                }
            }
        }
    }
    __syncthreads();
    for (int j = tid; j < 81 * 32; j += 256) {
        const int r = j >> 5, c = j & 31;
        const float v = lsum[0][r][c] + lsum[1][r][c] + lsum[2][r][c] + lsum[3][r][c];
        unsafeAtomicAdd(&gsum[j], v);
    }
}

// Pass 2: aggregate hierarchy + Frechet-mean iteration for all 120 segments.
__global__ __launch_bounds__(256) void pass2_centroids(
        const float* __restrict__ gsum, const int* __restrict__ gcnt_i,
        float* __restrict__ cent, float* __restrict__ cnt_all,
        float* __restrict__ cnorm) {
    const int tid = threadIdx.x;
    const int lane = tid & 31;
    const int grp = tid >> 5;
    for (int t = grp; t < 120; t += (blockDim.x >> 5)) {
        int c0, n;
        if (t < 3)       { c0 = t * 27;        n = 27; }
        else if (t < 12) { c0 = (t - 3) * 9;   n = 9;  }
        else if (t < 39) { c0 = (t - 12) * 3;  n = 3;  }
        else             { c0 = (t - 39);      n = 1;  }
        float sum = 0.f, cnt = 0.f;
        for (int k = 0; k < n; ++k) {
            sum += gsum[(c0 + k) * 32 + lane];
            cnt += (float)gcnt_i[c0 + k];
        }
        const float em = sum / fmaxf(cnt, 1.0f);
        float m = em;
        {
            float norm = sqrtf(red32(m * m));
            if (norm > MAXR) m *= MAXR / (norm + 1e-12f);
        }
        for (int it = 0; it < 10; ++it) {
            float v = m + 0.1f * (em - m);
            float norm = sqrtf(red32(v * v));
            if (norm > MAXR) v *= MAXR / (norm + 1e-12f);
            m = v;
        }
        cent[t * 32 + lane] = m;
        float ny = red32(m * m);
        if (lane == 0) { cnt_all[t] = cnt; cnorm[t] = ny; }
    }
}

// Pass 3: per-point distances to 4 ancestor centroids, batched x4, DPP
// reductions, per-wave [81][4] LDS accumulator with rank-round RMW.
__global__ __launch_bounds__(256) void pass3_dist(
        const float* __restrict__ z, const int* __restrict__ idx,
        const float* __restrict__ cent, const float* __restrict__ cnorm,
        float* __restrict__ dsum, int B) {
    __shared__ float lcent[120 * 32];
    __shared__ float lcn[120];
    __shared__ float ld[4][81][4];
    const int tid = threadIdx.x;
    for (int j = tid; j < 120 * 32; j += 256) lcent[j] = cent[j];
    for (int j = tid; j < 120; j += 256) lcn[j] = cnorm[j];
    for (int j = tid; j < 4 * 81 * 4; j += 256) (&ld[0][0][0])[j] = 0.f;
    __syncthreads();

    const int w = tid >> 6;
    const int g = (tid & 63) >> 3;
    const int sub = tid & 7;
    const int STRIDE = gridDim.x * 128;
    const int base0 = blockIdx.x * 128 + w * 32 + g;
    const int nfull = B / STRIDE;
    const int toff[4] = {0, 3, 12, 39};
    const int tdiv[4] = {27, 9, 3, 1};

    for (int it = 0; it < nfull; ++it) {
        const int ib = it * STRIDE + base0;
        float4 xv[4];
        int s4v[4], rank[4];
        float dl[4][4];
#pragma unroll
        for (int b = 0; b < 4; ++b)
            xv[b] = *(const float4*)(z + (size_t)(ib + b * 8) * 32 + sub * 4);
#pragma unroll
        for (int b = 0; b < 4; ++b)
            s4v[b] = idx[ib + b * 8] / 243;
#pragma unroll
        for (int b = 0; b < 4; ++b) {
            float nx = red8_dpp(xv[b].x * xv[b].x + xv[b].y * xv[b].y +
                                xv[b].z * xv[b].z + xv[b].w * xv[b].w);
            float norm = sqrtf(nx);
            if (norm > MAXR) {
                float s = MAXR / (norm + 1e-12f);
                xv[b].x *= s; xv[b].y *= s; xv[b].z *= s; xv[b].w *= s;
                nx = nx * s * s;
            }
            const float omx = 1.0f - nx;
#pragma unroll
            for (int l = 0; l < 4; ++l) {
                const int t = toff[l] + s4v[b] / tdiv[l];
                const float4 c = *(const float4*)(lcent + t * 32 + sub * 4);
                const float dx = xv[b].x - c.x, dy = xv[b].y - c.y,
                            dz = xv[b].z - c.z, dw = xv[b].w - c.w;
                const float sq = red8_dpp(dx * dx + dy * dy + dz * dz + dw * dw);
                const float denom = fmaxf(omx * (1.0f - lcn[t]), 1e-12f);
                float tt = 2.0f * sq * __builtin_amdgcn_rcpf(denom);
                tt = fmaxf(tt, 1e-7f);
                // arccosh(1+t) = ln(1 + t + sqrt(t*(t+2)))
                dl[b][l] = __log2f(1.0f + tt + sqrtf(tt * (tt + 2.0f))) * 0.69314718056f;
            }
        }
#pragma unroll
        for (int b = 0; b < 4; ++b)
            rank[b] = dup_rank(s4v[b], g, sub);
#pragma unroll
        for (int b = 0; b < 4; ++b) {
            float* row = &ld[w][s4v[b]][0];
            for (int r = 0;; ++r) {
                if (!__any(rank[b] == r)) break;
                if (rank[b] == r && sub == 0) {
                    float4 cur = *(float4*)row;
                    cur.x += dl[b][0]; cur.y += dl[b][1];
                    cur.z += dl[b][2]; cur.w += dl[b][3];
                    *(float4*)row = cur;
                }
            }
        }
    }
    // generic tail (not executed for B = 1M with grid 512)
    if (B % STRIDE) {
        const int ib = nfull * STRIDE + base0;
        for (int b = 0; b < 4; ++b) {
            const int i = ib + b * 8;
            const bool act = i < B;
            float4 xv = act ? *(const float4*)(z + (size_t)i * 32 + sub * 4)
                            : make_float4(0.f, 0.f, 0.f, 0.f);
            int s4 = act ? idx[i] / 243 : 81 + g;
            float nx = red8_dpp(xv.x * xv.x + xv.y * xv.y + xv.z * xv.z + xv.w * xv.w);
            float norm = sqrtf(nx);
            if (norm > MAXR) {
                float s = MAXR / (norm + 1e-12f);
                xv.x *= s; xv.y *= s; xv.z *= s; xv.w *= s;
                nx = nx * s * s;
            }
            const float omx = 1.0f - nx;
            float dl[4];
#pragma unroll
            for (int l = 0; l < 4; ++l) {
                const int t = toff[l] + (act ? s4 : 0) / tdiv[l];
                const float4 c = *(const float4*)(lcent + t * 32 + sub * 4);
                const float dx = xv.x - c.x, dy = xv.y - c.y,
                            dz = xv.z - c.z, dw = xv.w - c.w;
                const float sq = red8_dpp(dx * dx + dy * dy + dz * dz + dw * dw);
                const float denom = fmaxf(omx * (1.0f - lcn[t]), 1e-12f);
                float tt = 2.0f * sq * __builtin_amdgcn_rcpf(denom);
                tt = fmaxf(tt, 1e-7f);
                dl[l] = __log2f(1.0f + tt + sqrtf(tt * (tt + 2.0f))) * 0.69314718056f;
            }
            int rank = dup_rank(s4, g, sub);
            for (int r = 0;; ++r) {
                if (!__any(rank == r)) break;
                if (act && rank == r && sub == 0) {
                    float* row = &ld[w][s4][0];
                    float4 cur = *(float4*)row;
                    cur.x += dl[0]; cur.y += dl[1]; cur.z += dl[2]; cur.w += dl[3];
                    *(float4*)row = cur;
                }
            }
        }
    }
    __syncthreads();
    for (int j = tid; j < 81 * 4; j += 256) {
        const float v = (&ld[0][0][0])[j] + (&ld[1][0][0])[j] +
                        (&ld[2][0][0])[j] + (&ld[3][0][0])[j];
        unsafeAtomicAdd(&dsum[j], v);
    }
}

// Pass 4: finalize.
__global__ __launch_bounds__(128) void pass4_final(
        const float* __restrict__ dsum, const float* __restrict__ cnt_all,
        const float* __restrict__ w, float* __restrict__ out) {
    __shared__ float sl[81];
    __shared__ float su[81];
    const int tid = threadIdx.x;
    const int toff[4] = {0, 3, 12, 39};
    const int nsegs[4] = {3, 9, 27, 81};
    float total = 0.f;
    for (int l = 0; l < 4; ++l) {
        const int n_seg = nsegs[l];
        const int ch = 81 / n_seg;
        __syncthreads();
        if (tid < n_seg) {
            float cnt = cnt_all[toff[l] + tid];
            float ds = 0.f;
            for (int k = 0; k < ch; ++k) ds += dsum[(tid * ch + k) * 4 + l];
            sl[tid] = (cnt >= 2.0f) ? ds / fmaxf(cnt, 1.0f) : 0.f;
            su[tid] = (cnt > 0.0f) ? 1.f : 0.f;
        }
        __syncthreads();
        if (tid == 0) {
            float ll = 0.f, nu = 0.f;
            for (int s = 0; s < n_seg; ++s) { ll += sl[s]; nu += su[s]; }
            total += w[l] * ll / fmaxf(nu, 1.0f);
        }
    }
    if (tid == 0) out[0] = total;
}

extern "C" void kernel_launch(void* const* d_in, const int* in_sizes, int n_in,
                              void* d_out, int out_size, void* d_ws, size_t ws_size,
                              hipStream_t stream) {
    const float* z   = (const float*)d_in[0];
    const int*   idx = (const int*)d_in[1];
    const float* w   = (const float*)d_in[2];
    float* out = (float*)d_out;
    float* ws  = (float*)d_ws;
    const int B = in_sizes[1];

    float* gsum    = ws;                 // 2592
    float* dsum    = ws + 2592;          // 324
    int*   gcnt_i  = (int*)(ws + 2916);  // 81
    float* cent    = ws + 2997;          // 3840
    float* cnt_all = ws + 6837;          // 120
    float* cnorm   = ws + 6957;          // 120

    hipMemsetAsync(ws, 0, 2997 * sizeof(float), stream);
    pass0_count<<<256, 256, 0, stream>>>(idx, gcnt_i, B);
    pass1_hist<<<512, 256, 0, stream>>>(z, idx, gsum, B);
    pass2_centroids<<<1, 256, 0, stream>>>(gsum, gcnt_i, cent, cnt_all, cnorm);
    pass3_dist<<<512, 256, 0, stream>>>(z, idx, cent, cnorm, dsum, B);
    pass4_final<<<1, 128, 0, stream>>>(dsum, cnt_all, w, out);
}